// Round 28
// baseline (43.225 us; speedup 1.0000x reference)
//
#include <hip/hip_runtime.h>

typedef float f32x4 __attribute__((ext_vector_type(4)));
typedef short bf16x8 __attribute__((ext_vector_type(8)));

#define LOG2E 1.4426950408889634f
#define LN2   0.6931471805599453
#define PSEG  64
#define BURN  5

// Fully-fused MFMA-batched segmented CRF NLL. 512 blocks x 256 threads =
// 4 waves x 16 chains (PSEG=64, BURN=5). vs R27 (43.0us, absmax 0.0):
// (1) the U->LDS->read B-fragment exchange is replaced by a PURE LANE
// PERMUTATION: lane (cl,gq) needs rows 8gq..8gq+7 of chain cl, which live as
// whole f32x4s in lanes cl+16*((2gq)&3) / cl+16*((2gq+1)&3) of U0/U1 (kt=0)
// or U2/U3 (kt=1) [D-layout r=16m+4gq+j]. 8 cndmask selects + 16 ds_bpermute
// (2 hoisted address regs) replace 4 ds_write_b128 + wait + 4 ds_read_b128 --
// one LDS phase instead of two dependent phases; bit-identical values.
// (2) BURN 6->5: seam err 0.4*k^4*ln2 ~ 3e-5/seam, 63 seams ~ 1 output ulp;
// no clamped seams at PSEG=64 (toff(c=1)=n-4>=4); renorm at i=7 >= BURN.
// Rest identical to R27: renorm every 8 (exact pow2), merged length+gold
// prologue, in-block combine, T[end,:] on last non-empty chain, PINA pins.

__device__ __forceinline__ unsigned cvtpk(float a, float b) {
    unsigned r;
    asm("v_cvt_pk_bf16_f32 %0, %1, %2" : "=v"(r) : "v"(a), "v"(b));
    return r;
}

union FRAG { unsigned u[4]; bf16x8 s; };

#define SPLIT8(qa, qb, FH, FL) do { \
    unsigned h0 = cvtpk((qa).x, (qa).y); \
    unsigned h1 = cvtpk((qa).z, (qa).w); \
    unsigned h2 = cvtpk((qb).x, (qb).y); \
    unsigned h3 = cvtpk((qb).z, (qb).w); \
    float r0 = (qa).x - __uint_as_float(h0 << 16); \
    float r1 = (qa).y - __uint_as_float(h0 & 0xffff0000u); \
    float r2 = (qa).z - __uint_as_float(h1 << 16); \
    float r3 = (qa).w - __uint_as_float(h1 & 0xffff0000u); \
    float r4 = (qb).x - __uint_as_float(h2 << 16); \
    float r5 = (qb).y - __uint_as_float(h2 & 0xffff0000u); \
    float r6 = (qb).z - __uint_as_float(h3 << 16); \
    float r7 = (qb).w - __uint_as_float(h3 & 0xffff0000u); \
    (FH).u[0] = h0; (FH).u[1] = h1; (FH).u[2] = h2; (FH).u[3] = h3; \
    (FL).u[0] = cvtpk(r0, r1); (FL).u[1] = cvtpk(r2, r3); \
    (FL).u[2] = cvtpk(r4, r5); (FL).u[3] = cvtpk(r6, r7); \
} while (0)

// A-fragment (E row-tile mm, k-tile kt), prescaled 2^-7, split hi/lo.
#define BUILD_A(mm, kt, FH, FL) do { \
    const int ar = 16*(mm) + cl; \
    const int kb = 32*(kt) + 8*gq; \
    f32x4 qa, qb; \
    qa.x = __builtin_amdgcn_exp2f(Tm[ar*L + kb + 0] * LOG2E) * SC; \
    qa.y = __builtin_amdgcn_exp2f(Tm[ar*L + kb + 1] * LOG2E) * SC; \
    qa.z = __builtin_amdgcn_exp2f(Tm[ar*L + kb + 2] * LOG2E) * SC; \
    qa.w = __builtin_amdgcn_exp2f(Tm[ar*L + kb + 3] * LOG2E) * SC; \
    qb.x = __builtin_amdgcn_exp2f(Tm[ar*L + kb + 4] * LOG2E) * SC; \
    qb.y = __builtin_amdgcn_exp2f(Tm[ar*L + kb + 5] * LOG2E) * SC; \
    qb.z = __builtin_amdgcn_exp2f(Tm[ar*L + kb + 6] * LOG2E) * SC; \
    qb.w = __builtin_amdgcn_exp2f(Tm[ar*L + kb + 7] * LOG2E) * SC; \
    SPLIT8(qa, qb, FH, FL); \
} while (0)

// Pin the 16 E-fragments to VGPRs (defeats in-loop rematerialization).
#define PINA() asm volatile("" \
    : "+v"(ah00.s), "+v"(ah01.s), "+v"(ah10.s), "+v"(ah11.s), \
      "+v"(ah20.s), "+v"(ah21.s), "+v"(ah30.s), "+v"(ah31.s), \
      "+v"(al00.s), "+v"(al01.s), "+v"(al10.s), "+v"(al11.s), \
      "+v"(al20.s), "+v"(al21.s), "+v"(al30.s), "+v"(al31.s))

#define EXPV(d, s_) do { \
    (d).x = __builtin_amdgcn_exp2f((s_).x * LOG2E); \
    (d).y = __builtin_amdgcn_exp2f((s_).y * LOG2E); \
    (d).z = __builtin_amdgcn_exp2f((s_).z * LOG2E); \
    (d).w = __builtin_amdgcn_exp2f((s_).w * LOG2E); \
} while (0)

#define MFMA(a_, b_, c_) __builtin_amdgcn_mfma_f32_16x16x32_bf16((a_).s, (b_).s, (c_), 0, 0, 0)

#define MME(AH0, AH1, AL0, AL1, ELV, UD) do { \
    f32x4 accA = MFMA(AH0, BH0, zz); \
    accA = MFMA(AH1, BH1, accA); \
    accA = MFMA(AH0, BL0, accA); \
    f32x4 accB = MFMA(AH1, BL1, zz); \
    accB = MFMA(AL0, BH0, accB); \
    accB = MFMA(AL1, BH1, accB); \
    f32x4 un = (accA + accB) * (ELV); \
    (UD).x = act ? un.x : (UD).x; \
    (UD).y = act ? un.y : (UD).y; \
    (UD).z = act ? un.z : (UD).z; \
    (UD).w = act ? un.w : (UD).w; \
} while (0)

#define LOADL(D0, D1, D2, D3, tt) do { \
    const float* lp_ = lg + (size_t)(tt) * 64 + 4*gq; \
    (D0) = *(const f32x4*)(lp_); \
    (D1) = *(const f32x4*)(lp_ + 16); \
    (D2) = *(const f32x4*)(lp_ + 32); \
    (D3) = *(const f32x4*)(lp_ + 48); \
} while (0)

#define CLT(t_) ((t_) < 1 ? 1 : ((t_) > NP ? NP : (t_)))

// lane-permute a whole f32x4 (4 independent ds_bpermute, shared byte addr)
#define SHUF4(dst, V, ab) do { \
    (dst).x = __uint_as_float((unsigned)__builtin_amdgcn_ds_bpermute((ab), __float_as_int((V).x))); \
    (dst).y = __uint_as_float((unsigned)__builtin_amdgcn_ds_bpermute((ab), __float_as_int((V).y))); \
    (dst).z = __uint_as_float((unsigned)__builtin_amdgcn_ds_bpermute((ab), __float_as_int((V).z))); \
    (dst).w = __uint_as_float((unsigned)__builtin_amdgcn_ds_bpermute((ab), __float_as_int((V).w))); \
} while (0)

// One recursion step using register set (Lr0..Lr3) for step index ii;
// immediately reissues the SAME register set's load for step ii+2.
// B-fragment exchange via lane permutation (no LDS round-trip):
//   VA = (gq<2)?U0:U1, VB = (gq<2)?U2:U3;
//   qa0=perm(VA,adr0) qb0=perm(VA,adr1) qa1=perm(VB,adr0) qb1=perm(VB,adr1)
#define STEP_ONE(Lr0, Lr1, Lr2, Lr3, ii) do { \
    const int i_ = (ii); \
    const bool act = (i_ < endv); \
    f32x4 e0v, e1v, e2v, e3v; \
    EXPV(e0v, Lr0); EXPV(e1v, Lr1); EXPV(e2v, Lr2); EXPV(e3v, Lr3); \
    LOADL(Lr0, Lr1, Lr2, Lr3, CLT(toff + i_ + 2)); \
    f32x4 VA, VB; \
    VA.x = lowg ? U0.x : U1.x; VA.y = lowg ? U0.y : U1.y; \
    VA.z = lowg ? U0.z : U1.z; VA.w = lowg ? U0.w : U1.w; \
    VB.x = lowg ? U2.x : U3.x; VB.y = lowg ? U2.y : U3.y; \
    VB.z = lowg ? U2.z : U3.z; VB.w = lowg ? U2.w : U3.w; \
    f32x4 qa0, qb0, qa1, qb1; \
    SHUF4(qa0, VA, adr0); \
    SHUF4(qb0, VA, adr1); \
    SHUF4(qa1, VB, adr0); \
    SHUF4(qb1, VB, adr1); \
    FRAG BH0, BL0, BH1, BL1; \
    SPLIT8(qa0, qb0, BH0, BL0); \
    SPLIT8(qa1, qb1, BH1, BL1); \
    MME(ah00, ah01, al00, al01, e0v, U0); \
    MME(ah10, ah11, al10, al11, e1v, U1); \
    MME(ah20, ah21, al20, al21, e2v, U2); \
    MME(ah30, ah31, al30, al31, e3v, U3); \
    if ((i_ & 7) == 7) {  /* exact pow2 renorm; first at i=7 >= BURN */ \
        int rb = __builtin_amdgcn_ds_bpermute(cl << 2, __float_as_int(U0.x)); \
        unsigned eb = ((unsigned)rb >> 23) & 0xffu; \
        int e = (int)eb - 127; \
        float mlt = __uint_as_float((unsigned)(254 - (int)eb) << 23); \
        U0 *= mlt; U1 *= mlt; U2 *= mlt; U3 *= mlt; \
        M2 += e; \
    } \
    if (i_ == BURN - 1) { \
        float ps = U0.x+U0.y+U0.z+U0.w + U1.x+U1.y+U1.z+U1.w \
                 + U2.x+U2.y+U2.z+U2.w + U3.x+U3.y+U3.z+U3.w; \
        ps += __shfl_xor(ps, 16); ps += __shfl_xor(ps, 32); \
        sslog = __builtin_amdgcn_logf(ps); \
    } \
} while (0)

#define WSUM(x) do { _Pragma("unroll") \
    for (int off_ = 32; off_; off_ >>= 1) (x) += __shfl_xor((x), off_); } while (0)

__global__ __launch_bounds__(256, 1)
void crf_fused_kernel(const float* __restrict__ logits,
                      const float* __restrict__ Tm,
                      const int*   __restrict__ labels,
                      const int*   __restrict__ mask_g,
                      float*       __restrict__ out,
                      int S)
{
    const int b   = blockIdx.x;
    const int tid = threadIdx.x;
    const int wid = tid >> 6;              // wave 0..3
    const int l   = tid & 63;
    const int cl  = l & 15;                // local chain / fragment column
    const int gq  = l >> 4;                // lane group
    const int c   = 16 * wid + cl;         // global segment 0..63
    constexpr int L = 66, START = 64, END = 65;
    const float SC = 0.0078125f;           // 2^-7, exact

    __shared__ double redG[64];
    __shared__ float  redF[4];
    __shared__ int    redI[4];

    // hoisted bpermute byte addresses for the B-fragment lane permutation
    const bool lowg = (gq < 2);
    const int  adr0 = (cl + 16 * ((2 * gq)     & 3)) << 2;
    const int  adr1 = (cl + 16 * ((2 * gq + 1) & 3)) << 2;

    const float* lg  = logits + (size_t)b * S * 64;
    const int*   lab = labels + (size_t)b * S;
    const int*   msk = mask_g + (size_t)b * S;

    // ---- merged length + gold pass: 256 threads stride S (4 positions/lane)
    {
        int   lsum = 0;
        float gsum = 0.0f;
        #pragma unroll
        for (int q = 0; q < 4; ++q) {
            int t0 = tid + 256 * q;
            int mm = msk[t0];
            lsum += mm;
            if (mm) {
                int lc = lab[t0];
                float ga = lg[(size_t)t0 * 64 + lc];
                if (t0 > 0) ga += Tm[lc * L + lab[t0 - 1]];
                gsum += ga;
            }
        }
        WSUM(lsum);
        WSUM(gsum);
        if (l == 0) { redI[wid] = lsum; redF[wid] = gsum; }
    }
    __syncthreads();
    const int len = redI[0] + redI[1] + redI[2] + redI[3];
    const int NP  = len - 1;

    const int n = (NP + PSEG - 1) / PSEG;
    int spanv = NP - c * n;
    spanv = (spanv < 0) ? 0 : ((spanv > n) ? n : spanv);
    const int endv = (c == 0) ? n : (BURN + spanv);
    const int toff = (c == 0) ? 1 : (c * n - (BURN - 1));
    const int I = n + BURN;
    const bool lastc = (c * n < NP) && ((c + 1) * n >= NP);  // last non-empty

    // ---- E fragments: 4 row-tiles x 2 k-tiles, hi/lo
    FRAG ah00, ah01, ah10, ah11, ah20, ah21, ah30, ah31;
    FRAG al00, al01, al10, al11, al20, al21, al30, al31;
    BUILD_A(0, 0, ah00, al00); BUILD_A(0, 1, ah01, al01);
    BUILD_A(1, 0, ah10, al10); BUILD_A(1, 1, ah11, al11);
    BUILD_A(2, 0, ah20, al20); BUILD_A(2, 1, ah21, al21);
    BUILD_A(3, 0, ah30, al30); BUILD_A(3, 1, ah31, al31);
    PINA();

    // ---- state init: chain 0 = exact t=0 init; others = all-ones seed
    f32x4 U0, U1, U2, U3;
    {
        const bool c0 = (c == 0);
        #define INITU(mm, UD) do { \
            int r0 = 16*(mm) + 4*gq; \
            (UD).x = c0 ? __builtin_amdgcn_exp2f((lg[r0+0] + Tm[(r0+0)*L + START]) * LOG2E) : 1.0f; \
            (UD).y = c0 ? __builtin_amdgcn_exp2f((lg[r0+1] + Tm[(r0+1)*L + START]) * LOG2E) : 1.0f; \
            (UD).z = c0 ? __builtin_amdgcn_exp2f((lg[r0+2] + Tm[(r0+2)*L + START]) * LOG2E) : 1.0f; \
            (UD).w = c0 ? __builtin_amdgcn_exp2f((lg[r0+3] + Tm[(r0+3)*L + START]) * LOG2E) : 1.0f; \
        } while (0)
        INITU(0, U0); INITU(1, U1); INITU(2, U2); INITU(3, U3);
    }

    int    M2    = 0;
    float  sslog = 0.0f;
    f32x4  LA0, LA1, LA2, LA3, LB0, LB1, LB2, LB3;
    LOADL(LA0, LA1, LA2, LA3, CLT(toff));
    LOADL(LB0, LB1, LB2, LB3, CLT(toff + 1));
    const f32x4 zz = {0.f, 0.f, 0.f, 0.f};

    // ---- main loop: unrolled by 2 with alternating register sets, no copies
    int i = 0;
    #pragma clang loop unroll(disable)
    for (; i + 1 < I; i += 2) {
        PINA();
        STEP_ONE(LA0, LA1, LA2, LA3, i);
        STEP_ONE(LB0, LB1, LB2, LB3, i + 1);
    }
    if (i < I) {
        STEP_ONE(LA0, LA1, LA2, LA3, i);
    }

    // ---- final combine factor e^{T[end,row]} for the LAST NON-EMPTY segment
    {
        const bool lc = lastc;
        #define ENDF(mm, UD) do { \
            int r0 = 16*(mm) + 4*gq; \
            (UD).x *= lc ? __builtin_amdgcn_exp2f(Tm[END*L + r0+0] * LOG2E) : 1.0f; \
            (UD).y *= lc ? __builtin_amdgcn_exp2f(Tm[END*L + r0+1] * LOG2E) : 1.0f; \
            (UD).z *= lc ? __builtin_amdgcn_exp2f(Tm[END*L + r0+2] * LOG2E) : 1.0f; \
            (UD).w *= lc ? __builtin_amdgcn_exp2f(Tm[END*L + r0+3] * LOG2E) : 1.0f; \
        } while (0)
        ENDF(0, U0); ENDF(1, U1); ENDF(2, U2); ENDF(3, U3);
    }
    float Sv = U0.x+U0.y+U0.z+U0.w + U1.x+U1.y+U1.z+U1.w
             + U2.x+U2.y+U2.z+U2.w + U3.x+U3.y+U3.z+U3.w;
    Sv += __shfl_xor(Sv, 16); Sv += __shfl_xor(Sv, 32);

    double G = (double)M2 + 7.0 * (double)spanv
             + (double)__builtin_amdgcn_logf(Sv);
    if (c > 0) G -= (double)sslog;
    if (l < 16) redG[c] = G;

    // ---- in-block combine: out[b] = ln2 * sum_c G_c - gold
    __syncthreads();
    if (wid == 0) {
        double g = redG[l];
        #pragma unroll
        for (int off = 32; off; off >>= 1) g += __shfl_xor(g, off);
        if (l == 0) {
            float goldall = redF[0] + redF[1] + redF[2] + redF[3]
                          + Tm[lab[0] * L + START] + Tm[END * L + lab[len - 1]];
            out[b] = (float)(g * LN2 - (double)goldall);
        }
    }
}

extern "C" void kernel_launch(void* const* d_in, const int* in_sizes, int n_in,
                              void* d_out, int out_size, void* d_ws, size_t ws_size,
                              hipStream_t stream) {
    const float* logits = (const float*)d_in[0];
    const float* Tm     = (const float*)d_in[1];
    const int*   labels = (const int*)d_in[2];
    const int*   mask   = (const int*)d_in[3];
    float*       out    = (float*)d_out;

    const int B = out_size;                 // 512
    const int S = in_sizes[2] / B;          // 1024

    crf_fused_kernel<<<dim3(B), dim3(256), 0, stream>>>(logits, Tm, labels, mask, out, S);
}

// Round 29
// 42.432 us; speedup vs baseline: 1.0187x; 1.0187x over previous
//
#include <hip/hip_runtime.h>

typedef float f32x4 __attribute__((ext_vector_type(4)));
typedef short bf16x8 __attribute__((ext_vector_type(8)));

#define LOG2E 1.4426950408889634f
#define LN2   0.6931471805599453
#define PSEG  64
#define BURN  6

// Fully-fused MFMA-batched segmented CRF NLL -- RESTORE of R25, the best
// verified kernel (42.5us, absmax 0.0). R26 (dual-stream) and R28 (bpermute
// lane-permute) both broke numerics (absmax 64/32) with no speed gain; the
// LDS round-trip exchange below is the PROVEN-correct transport.
// 512 blocks x 256 threads = 4 waves x 16 chains (PSEG=64, BURN=6).
// Per chain: U->LDS (stride-68) -> B-frags (v_cvt_pk_bf16_f32 hi/lo,
// 3-product split) -> 24 MFMAs -> *exp(logits) -> freeze-mask. Exact pow2
// renorm every 4 steps (bpermute on chain scale rep); burn-in telescoped via
// sslog; T[end,:] on last non-empty chain; empty chains telescope to G=0.
// Gold + length + combine in-block; single launch. E-fragments PINA-pinned.

__device__ __forceinline__ unsigned cvtpk(float a, float b) {
    unsigned r;
    asm("v_cvt_pk_bf16_f32 %0, %1, %2" : "=v"(r) : "v"(a), "v"(b));
    return r;
}

union FRAG { unsigned u[4]; bf16x8 s; };

#define SPLIT8(qa, qb, FH, FL) do { \
    unsigned h0 = cvtpk((qa).x, (qa).y); \
    unsigned h1 = cvtpk((qa).z, (qa).w); \
    unsigned h2 = cvtpk((qb).x, (qb).y); \
    unsigned h3 = cvtpk((qb).z, (qb).w); \
    float r0 = (qa).x - __uint_as_float(h0 << 16); \
    float r1 = (qa).y - __uint_as_float(h0 & 0xffff0000u); \
    float r2 = (qa).z - __uint_as_float(h1 << 16); \
    float r3 = (qa).w - __uint_as_float(h1 & 0xffff0000u); \
    float r4 = (qb).x - __uint_as_float(h2 << 16); \
    float r5 = (qb).y - __uint_as_float(h2 & 0xffff0000u); \
    float r6 = (qb).z - __uint_as_float(h3 << 16); \
    float r7 = (qb).w - __uint_as_float(h3 & 0xffff0000u); \
    (FH).u[0] = h0; (FH).u[1] = h1; (FH).u[2] = h2; (FH).u[3] = h3; \
    (FL).u[0] = cvtpk(r0, r1); (FL).u[1] = cvtpk(r2, r3); \
    (FL).u[2] = cvtpk(r4, r5); (FL).u[3] = cvtpk(r6, r7); \
} while (0)

// A-fragment (E row-tile mm, k-tile kt), prescaled 2^-7, split hi/lo.
#define BUILD_A(mm, kt, FH, FL) do { \
    const int ar = 16*(mm) + cl; \
    const int kb = 32*(kt) + 8*gq; \
    f32x4 qa, qb; \
    qa.x = __builtin_amdgcn_exp2f(Tm[ar*L + kb + 0] * LOG2E) * SC; \
    qa.y = __builtin_amdgcn_exp2f(Tm[ar*L + kb + 1] * LOG2E) * SC; \
    qa.z = __builtin_amdgcn_exp2f(Tm[ar*L + kb + 2] * LOG2E) * SC; \
    qa.w = __builtin_amdgcn_exp2f(Tm[ar*L + kb + 3] * LOG2E) * SC; \
    qb.x = __builtin_amdgcn_exp2f(Tm[ar*L + kb + 4] * LOG2E) * SC; \
    qb.y = __builtin_amdgcn_exp2f(Tm[ar*L + kb + 5] * LOG2E) * SC; \
    qb.z = __builtin_amdgcn_exp2f(Tm[ar*L + kb + 6] * LOG2E) * SC; \
    qb.w = __builtin_amdgcn_exp2f(Tm[ar*L + kb + 7] * LOG2E) * SC; \
    SPLIT8(qa, qb, FH, FL); \
} while (0)

// Pin the 16 E-fragments to VGPRs (defeats in-loop rematerialization).
#define PINA() asm volatile("" \
    : "+v"(ah00.s), "+v"(ah01.s), "+v"(ah10.s), "+v"(ah11.s), \
      "+v"(ah20.s), "+v"(ah21.s), "+v"(ah30.s), "+v"(ah31.s), \
      "+v"(al00.s), "+v"(al01.s), "+v"(al10.s), "+v"(al11.s), \
      "+v"(al20.s), "+v"(al21.s), "+v"(al30.s), "+v"(al31.s))

#define EXPV(d, s_) do { \
    (d).x = __builtin_amdgcn_exp2f((s_).x * LOG2E); \
    (d).y = __builtin_amdgcn_exp2f((s_).y * LOG2E); \
    (d).z = __builtin_amdgcn_exp2f((s_).z * LOG2E); \
    (d).w = __builtin_amdgcn_exp2f((s_).w * LOG2E); \
} while (0)

#define MFMA(a_, b_, c_) __builtin_amdgcn_mfma_f32_16x16x32_bf16((a_).s, (b_).s, (c_), 0, 0, 0)

#define MME(AH0, AH1, AL0, AL1, ELV, UD) do { \
    f32x4 accA = MFMA(AH0, BH0, zz); \
    accA = MFMA(AH1, BH1, accA); \
    accA = MFMA(AH0, BL0, accA); \
    f32x4 accB = MFMA(AH1, BL1, zz); \
    accB = MFMA(AL0, BH0, accB); \
    accB = MFMA(AL1, BH1, accB); \
    f32x4 un = (accA + accB) * (ELV); \
    (UD).x = act ? un.x : (UD).x; \
    (UD).y = act ? un.y : (UD).y; \
    (UD).z = act ? un.z : (UD).z; \
    (UD).w = act ? un.w : (UD).w; \
} while (0)

#define LOADL(D0, D1, D2, D3, tt) do { \
    const float* lp_ = lg + (size_t)(tt) * 64 + 4*gq; \
    (D0) = *(const f32x4*)(lp_); \
    (D1) = *(const f32x4*)(lp_ + 16); \
    (D2) = *(const f32x4*)(lp_ + 32); \
    (D3) = *(const f32x4*)(lp_ + 48); \
} while (0)

#define CLT(t_) ((t_) < 1 ? 1 : ((t_) > NP ? NP : (t_)))

// One recursion step using register set (Lr0..Lr3) for step index ii;
// immediately reissues the SAME register set's load for step ii+2.
#define STEP_ONE(Lr0, Lr1, Lr2, Lr3, ii) do { \
    const int i_ = (ii); \
    const bool act = (i_ < endv); \
    f32x4 e0v, e1v, e2v, e3v; \
    EXPV(e0v, Lr0); EXPV(e1v, Lr1); EXPV(e2v, Lr2); EXPV(e3v, Lr3); \
    LOADL(Lr0, Lr1, Lr2, Lr3, CLT(toff + i_ + 2)); \
    *(f32x4*)&Ub[cl*68 +  0 + 4*gq] = U0; \
    *(f32x4*)&Ub[cl*68 + 16 + 4*gq] = U1; \
    *(f32x4*)&Ub[cl*68 + 32 + 4*gq] = U2; \
    *(f32x4*)&Ub[cl*68 + 48 + 4*gq] = U3; \
    f32x4 qa0 = *(const f32x4*)&Ub[cl*68 +      8*gq]; \
    f32x4 qb0 = *(const f32x4*)&Ub[cl*68 +  4 + 8*gq]; \
    f32x4 qa1 = *(const f32x4*)&Ub[cl*68 + 32 + 8*gq]; \
    f32x4 qb1 = *(const f32x4*)&Ub[cl*68 + 36 + 8*gq]; \
    FRAG BH0, BL0, BH1, BL1; \
    SPLIT8(qa0, qb0, BH0, BL0); \
    SPLIT8(qa1, qb1, BH1, BL1); \
    MME(ah00, ah01, al00, al01, e0v, U0); \
    MME(ah10, ah11, al10, al11, e1v, U1); \
    MME(ah20, ah21, al20, al21, e2v, U2); \
    MME(ah30, ah31, al30, al31, e3v, U3); \
    if ((i_ & 3) == 3) { \
        int rb = __builtin_amdgcn_ds_bpermute(cl << 2, __float_as_int(U0.x)); \
        unsigned eb = ((unsigned)rb >> 23) & 0xffu; \
        int e = (int)eb - 127; \
        float mlt = __uint_as_float((unsigned)(254 - (int)eb) << 23); \
        U0 *= mlt; U1 *= mlt; U2 *= mlt; U3 *= mlt; \
        bool cnt = (c == 0) || (i_ >= BURN); \
        M2 += cnt ? e : 0; \
    } \
    if (i_ == BURN - 1) { \
        float ps = U0.x+U0.y+U0.z+U0.w + U1.x+U1.y+U1.z+U1.w \
                 + U2.x+U2.y+U2.z+U2.w + U3.x+U3.y+U3.z+U3.w; \
        ps += __shfl_xor(ps, 16); ps += __shfl_xor(ps, 32); \
        sslog = __builtin_amdgcn_logf(ps); \
    } \
} while (0)

#define WSUM(x) do { _Pragma("unroll") \
    for (int off_ = 32; off_; off_ >>= 1) (x) += __shfl_xor((x), off_); } while (0)

__global__ __launch_bounds__(256, 1)
void crf_fused_kernel(const float* __restrict__ logits,
                      const float* __restrict__ Tm,
                      const int*   __restrict__ labels,
                      const int*   __restrict__ mask_g,
                      float*       __restrict__ out,
                      int S)
{
    const int b   = blockIdx.x;
    const int tid = threadIdx.x;
    const int wid = tid >> 6;              // wave 0..3
    const int l   = tid & 63;
    const int cl  = l & 15;                // local chain / fragment column
    const int gq  = l >> 4;                // lane group
    const int c   = 16 * wid + cl;         // global segment 0..63
    constexpr int L = 66, START = 64, END = 65;
    const float SC = 0.0078125f;           // 2^-7, exact

    __shared__ __align__(16) float Ubs[4][16 * 68]; // per-wave [chain][state]
    __shared__ double redG[64];
    __shared__ float  redF[4];
    float* Ub = &Ubs[wid][0];

    const float* lg  = logits + (size_t)b * S * 64;
    const int*   lab = labels + (size_t)b * S;
    const int*   msk = mask_g + (size_t)b * S;

    // ---- length (per-wave, identical result on every wave)
    int lensum = 0;
    #pragma unroll 4
    for (int t0 = l; t0 < S; t0 += 64) lensum += msk[t0];
    WSUM(lensum);
    const int len = lensum, NP = len - 1;

    // ---- gold partial: 256 threads stride the sequence (4 gathers/lane)
    {
        float gsum = 0.0f;
        #pragma unroll
        for (int q = 0; q < 4; ++q) {
            int t0 = tid + 256 * q;
            if (t0 < len) {
                int lc = lab[t0];
                float ga = lg[(size_t)t0 * 64 + lc];
                if (t0 > 0) ga += Tm[lc * L + lab[t0 - 1]];
                gsum += ga;
            }
        }
        WSUM(gsum);
        if (l == 0) redF[wid] = gsum;
    }

    const int n = (NP + PSEG - 1) / PSEG;
    int spanv = NP - c * n;
    spanv = (spanv < 0) ? 0 : ((spanv > n) ? n : spanv);
    const int endv = (c == 0) ? n : (BURN + spanv);
    const int toff = (c == 0) ? 1 : (c * n - (BURN - 1));
    const int I = n + BURN;
    const bool lastc = (c * n < NP) && ((c + 1) * n >= NP);  // last non-empty

    // ---- E fragments: 4 row-tiles x 2 k-tiles, hi/lo
    FRAG ah00, ah01, ah10, ah11, ah20, ah21, ah30, ah31;
    FRAG al00, al01, al10, al11, al20, al21, al30, al31;
    BUILD_A(0, 0, ah00, al00); BUILD_A(0, 1, ah01, al01);
    BUILD_A(1, 0, ah10, al10); BUILD_A(1, 1, ah11, al11);
    BUILD_A(2, 0, ah20, al20); BUILD_A(2, 1, ah21, al21);
    BUILD_A(3, 0, ah30, al30); BUILD_A(3, 1, ah31, al31);
    PINA();

    // ---- state init: chain 0 = exact t=0 init; others = all-ones seed
    f32x4 U0, U1, U2, U3;
    {
        const bool c0 = (c == 0);
        #define INITU(mm, UD) do { \
            int r0 = 16*(mm) + 4*gq; \
            (UD).x = c0 ? __builtin_amdgcn_exp2f((lg[r0+0] + Tm[(r0+0)*L + START]) * LOG2E) : 1.0f; \
            (UD).y = c0 ? __builtin_amdgcn_exp2f((lg[r0+1] + Tm[(r0+1)*L + START]) * LOG2E) : 1.0f; \
            (UD).z = c0 ? __builtin_amdgcn_exp2f((lg[r0+2] + Tm[(r0+2)*L + START]) * LOG2E) : 1.0f; \
            (UD).w = c0 ? __builtin_amdgcn_exp2f((lg[r0+3] + Tm[(r0+3)*L + START]) * LOG2E) : 1.0f; \
        } while (0)
        INITU(0, U0); INITU(1, U1); INITU(2, U2); INITU(3, U3);
    }

    int    M2    = 0;
    float  sslog = 0.0f;
    f32x4  LA0, LA1, LA2, LA3, LB0, LB1, LB2, LB3;
    LOADL(LA0, LA1, LA2, LA3, CLT(toff));
    LOADL(LB0, LB1, LB2, LB3, CLT(toff + 1));
    const f32x4 zz = {0.f, 0.f, 0.f, 0.f};

    // ---- main loop: unrolled by 2 with alternating register sets, no copies
    int i = 0;
    #pragma clang loop unroll(disable)
    for (; i + 1 < I; i += 2) {
        PINA();
        STEP_ONE(LA0, LA1, LA2, LA3, i);
        STEP_ONE(LB0, LB1, LB2, LB3, i + 1);
    }
    if (i < I) {
        STEP_ONE(LA0, LA1, LA2, LA3, i);
    }

    // ---- final combine factor e^{T[end,row]} for the LAST NON-EMPTY segment
    {
        const bool lc = lastc;
        #define ENDF(mm, UD) do { \
            int r0 = 16*(mm) + 4*gq; \
            (UD).x *= lc ? __builtin_amdgcn_exp2f(Tm[END*L + r0+0] * LOG2E) : 1.0f; \
            (UD).y *= lc ? __builtin_amdgcn_exp2f(Tm[END*L + r0+1] * LOG2E) : 1.0f; \
            (UD).z *= lc ? __builtin_amdgcn_exp2f(Tm[END*L + r0+2] * LOG2E) : 1.0f; \
            (UD).w *= lc ? __builtin_amdgcn_exp2f(Tm[END*L + r0+3] * LOG2E) : 1.0f; \
        } while (0)
        ENDF(0, U0); ENDF(1, U1); ENDF(2, U2); ENDF(3, U3);
    }
    float Sv = U0.x+U0.y+U0.z+U0.w + U1.x+U1.y+U1.z+U1.w
             + U2.x+U2.y+U2.z+U2.w + U3.x+U3.y+U3.z+U3.w;
    Sv += __shfl_xor(Sv, 16); Sv += __shfl_xor(Sv, 32);

    double G = (double)M2 + 7.0 * (double)spanv
             + (double)__builtin_amdgcn_logf(Sv);
    if (c > 0) G -= (double)sslog;
    if (l < 16) redG[c] = G;

    // ---- in-block combine: out[b] = ln2 * sum_c G_c - gold
    __syncthreads();
    if (wid == 0) {
        double g = redG[l];
        #pragma unroll
        for (int off = 32; off; off >>= 1) g += __shfl_xor(g, off);
        if (l == 0) {
            float goldall = redF[0] + redF[1] + redF[2] + redF[3]
                          + Tm[lab[0] * L + START] + Tm[END * L + lab[len - 1]];
            out[b] = (float)(g * LN2 - (double)goldall);
        }
    }
}

extern "C" void kernel_launch(void* const* d_in, const int* in_sizes, int n_in,
                              void* d_out, int out_size, void* d_ws, size_t ws_size,
                              hipStream_t stream) {
    const float* logits = (const float*)d_in[0];
    const float* Tm     = (const float*)d_in[1];
    const int*   labels = (const int*)d_in[2];
    const int*   mask   = (const int*)d_in[3];
    float*       out    = (float*)d_out;

    const int B = out_size;                 // 512
    const int S = in_sizes[2] / B;          // 1024

    crf_fused_kernel<<<dim3(B), dim3(256), 0, stream>>>(logits, Tm, labels, mask, out, S);
}